// Round 12
// baseline (572.823 us; speedup 1.0000x reference)
//
#include <hip/hip_runtime.h>
#include <hip/hip_bf16.h>

typedef unsigned short u16;
typedef unsigned char u8;
typedef unsigned long long u64;
typedef __attribute__((ext_vector_type(4))) int i32x4;
typedef __attribute__((ext_vector_type(8))) int i32x8;
typedef __attribute__((ext_vector_type(4))) float f32x4;

#define NROWS 4092      // 4 * 1023 valid token rows
#define NROWS_PAD 4096
#define DDIM 2048
#define VDIM 32768
#define NCHUNK 512      // 64-wide vocab chunks per row
#define SC8 0x7F7F7F7F  // e8m0 scale = 1.0 in all four bytes
#define BUFB 32768u     // LDS bytes per buffer: A 16K + B 16K

// ---------- helpers ----------
// RNE fp32 -> OCP e4m3fn (manual, incl. denormals + saturation to 448)
__device__ __forceinline__ u8 f2fp8(float f) {
  union { float f; unsigned u; } v; v.f = f;
  unsigned s = (v.u >> 24) & 0x80u;
  unsigned a = v.u & 0x7FFFFFFFu;
  if (a >= 0x43E80000u) return (u8)(s | 0x7E);   // |f| >= 464 -> 448
  int e = (int)(a >> 23) - 127;
  unsigned m = a & 0x7FFFFFu;
  if (e < -6) {                                   // denormal target
    unsigned full = m | 0x800000u;
    int sh = 20 + (-6 - e);
    if (sh > 31) return (u8)s;
    unsigned q = full >> sh;
    unsigned rem = full & ((1u << sh) - 1u), half = 1u << (sh - 1);
    q += (rem > half || (rem == half && (q & 1u)));
    return (u8)(s | q);
  }
  unsigned q = m >> 20, rem = m & 0xFFFFFu;
  q += (rem > 0x80000u || (rem == 0x80000u && (q & 1u)));
  unsigned bits = (((unsigned)(e + 7)) << 3) + q;
  if (bits >= 0x7Fu) bits = 0x7Eu;
  return (u8)(s | bits);
}

__device__ __forceinline__ void gload16(const void* g, void* l) {
  using gp_t = const __attribute__((address_space(1))) unsigned*;
  using lp_t = __attribute__((address_space(3))) unsigned*;
  __builtin_amdgcn_global_load_lds((gp_t)g, (lp_t)(unsigned)(unsigned long long)l,
                                   16, 0, 0);
}

#define BAR() __builtin_amdgcn_s_barrier()
#define SB()  __builtin_amdgcn_sched_barrier(0)
#define SHUF(a, b) __builtin_shufflevector(a, b, 0, 1, 2, 3, 4, 5, 6, 7)

// ---------- kernel 1: chosen ids (padded) + zero chlog/accum ----------
__global__ void init_k(const int* __restrict__ ids, int* __restrict__ chosen,
                       float* __restrict__ chlog, float* __restrict__ accum) {
  int i = blockIdx.x * 256 + threadIdx.x;
  if (i < NROWS_PAD) {
    int v = -1;
    if (i < NROWS) { int b = i / 1023, t = i % 1023; v = ids[b * 1024 + t + 1]; }
    chosen[i] = v;
    chlog[i] = 0.f;
  }
  if (i < 2) accum[i] = 0.f;
}

// ---------- kernel 1b: bucket chosen ids by 64-wide vocab tile ----------
__global__ void bucket_k(const int* __restrict__ chosen,
                         int* __restrict__ boff, int* __restrict__ bent) {
  __shared__ int cnt[512];
  __shared__ int base[512];
  int tid = threadIdx.x;             // 512 threads
  cnt[tid] = 0;
  __syncthreads();
  int loc[8], tile[8];
#pragma unroll
  for (int j = 0; j < 8; ++j) {
    int r = tid + (j << 9);
    int c = chosen[r];
    int ti = (c < 0) ? 512 : (c >> 6);
    tile[j] = ti;
    loc[j] = (ti < 512) ? atomicAdd(&cnt[ti], 1) : 0;
  }
  __syncthreads();
  if (tid == 0) {
    int s = 0;
    for (int i = 0; i < 512; ++i) { base[i] = s; s += cnt[i]; }
  }
  __syncthreads();
  boff[tid] = base[tid];
  if (tid == 511) boff[512] = base[511] + cnt[511];
#pragma unroll
  for (int j = 0; j < 8; ++j) {
    int r = tid + (j << 9);
    if (tile[j] < 512) bent[base[tile[j]] + loc[j]] = (r << 6) | (chosen[r] & 63);
  }
}

// ---------- kernel 2: h fp32 -> fp8 e4m3 (x16), row-remapped, padded ------
__global__ void conv_h(const float* __restrict__ hs, u8* __restrict__ h8) {
  int idx = blockIdx.x * 256 + threadIdx.x;   // 1,048,576 threads, 8 elems each
  int row = idx >> 8;
  int c8 = (idx & 255) << 3;
  u64 o = 0;
  if (row < NROWS) {
    int b = row / 1023, t = row % 1023;
    const float* p = hs + (size_t)((b << 10) + t) * DDIM + c8;
    float4 x = *(const float4*)p, y = *(const float4*)(p + 4);
    o = (u64)f2fp8(x.x * 16.f)        | ((u64)f2fp8(x.y * 16.f) << 8) |
        ((u64)f2fp8(x.z * 16.f) << 16) | ((u64)f2fp8(x.w * 16.f) << 24) |
        ((u64)f2fp8(y.x * 16.f) << 32) | ((u64)f2fp8(y.y * 16.f) << 40) |
        ((u64)f2fp8(y.z * 16.f) << 48) | ((u64)f2fp8(y.w * 16.f) << 56);
  }
  *(u64*)(h8 + (size_t)row * DDIM + c8) = o;
}

// ---------- kernel 3: W (D x V fp32) -> W^T (V x D fp8 e4m3 x64)
//            + EXACT fp32 chosen-logit partial dots (atomicAdd into chlog) ---
__global__ void transpose_w(const float* __restrict__ W, u8* __restrict__ WT8,
                            const float* __restrict__ hs,
                            const int* __restrict__ boff,
                            const int* __restrict__ bent,
                            float* __restrict__ chlog) {
  __shared__ float t32[64][65];     // [d][v] fp32 tile (exact dots)
  __shared__ u8 t8[64][68];         // [d][v] quantized
  int v0 = blockIdx.x << 6, d0 = blockIdx.y << 6;
  int tid = threadIdx.x;
  int vi = (tid & 15) << 2, dl = tid >> 4;
#pragma unroll
  for (int i = 0; i < 4; ++i) {
    int d = dl + (i << 4);
    float4 w = *(const float4*)(W + (size_t)(d0 + d) * VDIM + v0 + vi);
    t32[d][vi + 0] = w.x; t32[d][vi + 1] = w.y;
    t32[d][vi + 2] = w.z; t32[d][vi + 3] = w.w;
    t8[d][vi + 0] = f2fp8(w.x * 64.f); t8[d][vi + 1] = f2fp8(w.y * 64.f);
    t8[d][vi + 2] = f2fp8(w.z * 64.f); t8[d][vi + 3] = f2fp8(w.w * 64.f);
  }
  __syncthreads();
  // transposed fp8 write: wave-coalesced 16B chunks
  int vr = tid >> 2, dc = (tid & 3) << 4;
  union { u8 b[16]; ulonglong2 q; } u;
#pragma unroll
  for (int k = 0; k < 16; ++k) u.b[k] = t8[dc + k][vr];
  *(ulonglong2*)(WT8 + (size_t)(v0 + vr) * DDIM + d0 + dc) = u.q;
  // exact chosen dots from the pre-bucketed list: one wave per match
  int m0 = boff[blockIdx.x], m1 = boff[blockIdx.x + 1];
  int lane = tid & 63, wv = tid >> 6;
  for (int m = m0 + wv; m < m1; m += 4) {
    int e = bent[m];
    int r = e >> 6, cv = e & 63;
    int b = r / 1023, tt = r % 1023;
    float s = hs[(size_t)((b << 10) + tt) * DDIM + d0 + lane] * t32[lane][cv];
#pragma unroll
    for (int o = 1; o < 64; o <<= 1) s += __shfl_xor(s, o, 64);
    if (lane == 0) atomicAdd(chlog + r, s);
  }
}

// ---------- kernel 4: 128x128 fp8 GEMM (mfma_scale 16x16x128) + online-LSE -
// A8: [4096][2048] fp8 (x16, zero-padded rows), Bt8: [32768][2048] fp8 (x64)
// 4 waves (2x2), wave tile 64x64, acc 64 AGPR (no spill). LDS 64 KiB total:
// [buf(32768)][A 16K | B 16K] -> TWO blocks co-resident per CU = two
// independent barrier domains (block A's drain overlaps block B's MFMA).
// Slot map = R11's 0-conflict ((u<<2)|g4)^xr; counted vmcnt(4) boundary.
__global__ __launch_bounds__(256, 2) void gemm_lse(
    const u8* __restrict__ A, const u8* __restrict__ Bt,
    float2* __restrict__ partials) {
  extern __shared__ u16 smem[];
  char* lds = (char*)smem;

  const int tid = threadIdx.x;
  const int l = tid & 63;
  const int wid = tid >> 6;                // 4 waves
  const int wmr = wid >> 1, wnr = wid & 1; // 2 x 2
  const int ln = l & 15;
  const int g4 = l >> 4;
  const int xr = ln & 7;

  // XCD-bijective swizzle (8192 % 8 == 0): each XCD owns a 32x32 supertile
  int bid = blockIdx.x;
  int id = ((bid & 7) << 10) | (bid >> 3);
  int bm = id & 31;                  // 0..31  (M tiles of 128)
  int bn = id >> 5;                  // 0..255 (N tiles of 128)
  const int m0 = bm << 7, n0 = bn << 7;

  const u8* Ab = A + (size_t)m0 * DDIM;
  const u8* Bb = Bt + (size_t)n0 * DDIM;

  // swizzled LDS read offsets: half u at slot ((u<<2)|g4) ^ xr, 16B units
  const unsigned aA0 = (unsigned)(((wmr << 6) | ln) << 7) + (((0 | g4) ^ xr) << 4);
  const unsigned aA1 = (unsigned)(((wmr << 6) | ln) << 7) + (((4 | g4) ^ xr) << 4);
  const unsigned aB0 = 16384u + (unsigned)(((wnr << 6) | ln) << 7) + (((0 | g4) ^ xr) << 4);
  const unsigned aB1 = 16384u + (unsigned)(((wnr << 6) | ln) << 7) + (((4 | g4) ^ xr) << 4);

  // staging: lane voffsets (pre-permuted source); wave w stages segs
  // {w, 4+w, 8+w, 12+w} of 16 (8 rows each) for both A and B panels
  const int srow = l >> 3;
  const unsigned selb = (unsigned)(((l & 7) ^ srow) << 4);   // bytes
  const unsigned voff0 = (unsigned)((((0  + wid) << 3) | srow) * 2048) + selb;
  const unsigned voff1 = (unsigned)((((4  + wid) << 3) | srow) * 2048) + selb;
  const unsigned voff2 = (unsigned)((((8  + wid) << 3) | srow) * 2048) + selb;
  const unsigned voff3 = (unsigned)((((12 + wid) << 3) | srow) * 2048) + selb;
  const unsigned dA0 = (unsigned)(wid << 10),        dA1 = (unsigned)((4 + wid) << 10);
  const unsigned dA2 = (unsigned)((8 + wid) << 10),  dA3 = (unsigned)((12 + wid) << 10);

#define RFL(x) __builtin_amdgcn_readfirstlane((int)(x))
#define GLL(src, dst) gload16((src), lds + RFL(dst))
#define LD4(off) (*(const i32x4*)(lds + (off)))
#define FRAG(b0, b1, o) SHUF(LD4((b0) + (o)), LD4((b1) + (o)))

#define MFMA4(q, af) do {                                                      \
    __builtin_amdgcn_s_setprio(1);                                             \
    _Pragma("unroll")                                                          \
    for (int _ni = 0; _ni < 4; ++_ni)                                          \
      acc[(q)][_ni] = __builtin_amdgcn_mfma_scale_f32_16x16x128_f8f6f4(        \
          (af), bf[_ni], acc[(q)][_ni], 0, 0, 0, SC8, 0, SC8);                 \
    __builtin_amdgcn_s_setprio(0);                                             \
  } while (0)

  f32x4 acc[4][4] = {};

  // prologue: A(0),B(0) -> buf0; B(1) -> buf1; wait tile0, leave B(1) in flight
  GLL(Ab + voff0, dA0);           GLL(Ab + voff1, dA1);
  GLL(Ab + voff2, dA2);           GLL(Ab + voff3, dA3);
  GLL(Bb + voff0, 16384 + dA0);   GLL(Bb + voff1, 16384 + dA1);
  GLL(Bb + voff2, 16384 + dA2);   GLL(Bb + voff3, 16384 + dA3);
  GLL(Bb + 128 + voff0, BUFB + 16384 + dA0);
  GLL(Bb + 128 + voff1, BUFB + 16384 + dA1);
  GLL(Bb + 128 + voff2, BUFB + 16384 + dA2);
  GLL(Bb + 128 + voff3, BUFB + 16384 + dA3);
  asm volatile("s_waitcnt vmcnt(4)" ::: "memory"); SB();
  BAR();
  SB();

  for (int t = 0; t < 16; ++t) {
    const unsigned fb = (unsigned)(t & 1) * BUFB;    // current buf byte offset
    const unsigned fbn = BUFB - fb;                  // next buf
    const u8* baseA = Ab + ((t + 1) << 7);           // A(t+1), uniform
    const u8* baseB = Bb + ((t + 2) << 7);           // B(t+2), uniform
    const unsigned rA0 = fb + aA0, rA1 = fb + aA1;
    const unsigned rB0 = fb + aB0, rB1 = fb + aB1;

    // B operands for the whole tile (8 ds_read_b128 -> 4 x i32x8)
    i32x8 bf[4];
#pragma unroll
    for (int ni = 0; ni < 4; ++ni) bf[ni] = FRAG(rB0, rB1, ni * 2048);

    // ---- q0: A rows 0..15; stage A(t+1) segs 0,1
    i32x8 af = FRAG(rA0, rA1, 0);
    if (t < 15) { GLL(baseA + voff0, fbn + dA0); GLL(baseA + voff1, fbn + dA1); }
    MFMA4(0, af);
    // ---- q1: A rows 16..31; stage A(t+1) segs 2,3
    af = FRAG(rA0, rA1, 2048);
    if (t < 15) { GLL(baseA + voff2, fbn + dA2); GLL(baseA + voff3, fbn + dA3); }
    MFMA4(1, af);
    SB();
    BAR();   // mid-tile: all waves' bf consumed -> B-space(fb) writable
    SB();
    // ---- q2: A rows 32..47; stage B(t+2) segs 0,1
    af = FRAG(rA0, rA1, 4096);
    if (t < 14) { GLL(baseB + voff0, fb + 16384 + dA0);
                  GLL(baseB + voff1, fb + 16384 + dA1); }
    MFMA4(2, af);
    // ---- q3: A rows 48..63; stage B(t+2) segs 2,3; counted vmcnt; flip
    af = FRAG(rA0, rA1, 6144);
    if (t < 14) { GLL(baseB + voff2, fb + 16384 + dA2);
                  GLL(baseB + voff3, fb + 16384 + dA3); }
    MFMA4(3, af);
    if (t < 14)       { asm volatile("s_waitcnt vmcnt(4)" ::: "memory"); }
    else if (t == 14) { asm volatile("s_waitcnt vmcnt(0)" ::: "memory"); }
    SB();
    BAR();   // boundary: tile t+1 fully landed, flip buffer
    SB();
  }

  // epilogue: per-row (max, sum-exp) over this wave's 64 cols (scale /1024)
  // C/D layout: col = lane&15, row = (lane>>4)*4 + reg
  const int chunk = (bn << 1) | wnr;
#pragma unroll
  for (int mi = 0; mi < 4; ++mi) {
#pragma unroll
    for (int rr = 0; rr < 4; ++rr) {
      const int row = m0 + (wmr << 6) + (mi << 4) + (g4 << 2) + rr;
      float v0 = acc[mi][0][rr] * 0.0009765625f;
      float v1 = acc[mi][1][rr] * 0.0009765625f;
      float v2 = acc[mi][2][rr] * 0.0009765625f;
      float v3 = acc[mi][3][rr] * 0.0009765625f;
      float mx = fmaxf(fmaxf(v0, v1), fmaxf(v2, v3));
#pragma unroll
      for (int o = 1; o < 16; o <<= 1) mx = fmaxf(mx, __shfl_xor(mx, o, 64));
      float s = __expf(v0 - mx) + __expf(v1 - mx) + __expf(v2 - mx) + __expf(v3 - mx);
#pragma unroll
      for (int o = 1; o < 16; o <<= 1) s += __shfl_xor(s, o, 64);
      if (ln == 0) partials[(size_t)row * NCHUNK + chunk] = make_float2(mx, s);
    }
  }
#undef MFMA4
#undef FRAG
#undef LD4
#undef GLL
#undef RFL
}

// ---------- kernel 5: combine partials -> lse -> logps -> loss terms ----------
__global__ void reduce_lse(const float2* __restrict__ partials,
                           const float* __restrict__ chlog,
                           const float* __restrict__ oldlp,
                           const int* __restrict__ labels,
                           const float* __restrict__ adv,
                           float* __restrict__ out, float* __restrict__ accum) {
  const int wid = threadIdx.x >> 6, l = threadIdx.x & 63;
  const int row = blockIdx.x * 4 + wid;        // 1023*4 = 4092 exactly
  float M = -INFINITY, S = 0.f;
  for (int c = l; c < NCHUNK; c += 64) {
    float2 p = partials[(size_t)row * NCHUNK + c];
    float Mn = fmaxf(M, p.x);
    S = S * __expf(M - Mn) + p.y * __expf(p.x - Mn);
    M = Mn;
  }
#pragma unroll
  for (int o = 1; o < 64; o <<= 1) {
    float Mo = __shfl_xor(M, o, 64), So = __shfl_xor(S, o, 64);
    float Mn = fmaxf(M, Mo);
    S = S * __expf(M - Mn) + So * __expf(Mo - Mn);
    M = Mn;
  }
  if (l == 0) {
    float lse = M + __logf(S);
    float ptl = chlog[row] - lse;
    out[1 + row] = ptl;
    int b = row / 1023, t = row % 1023;
    float a = adv[b];
    float ratio = __expf(ptl - oldlp[row]);
    float l1 = ratio * a;
    float l2 = fminf(fmaxf(ratio, 0.8f), 1.3f) * a;
    float mk = (float)labels[b * 1024 + t + 1];
    atomicAdd(accum + 0, -fminf(l1, l2) * mk);
    atomicAdd(accum + 1, mk);
  }
}

__global__ void finalize_k(const float* __restrict__ accum, float* __restrict__ out) {
  out[0] = accum[0] / accum[1];
}

// ---------- launch ----------
extern "C" void kernel_launch(void* const* d_in, const int* in_sizes, int n_in,
                              void* d_out, int out_size, void* d_ws, size_t ws_size,
                              hipStream_t stream) {
  const float* hs     = (const float*)d_in[0];   // (4,1024,2048)
  const float* W      = (const float*)d_in[1];   // (2048,32768)
  const int*   ids    = (const int*)d_in[2];     // (4,1024)
  const int*   labels = (const int*)d_in[3];     // (4,1024)
  const float* adv    = (const float*)d_in[4];   // (4,)
  const float* oldlp  = (const float*)d_in[5];   // (4,1023)
  float* out = (float*)d_out;                    // [loss, 4092 x per_token_logps]

  // ws layout (~92.4 MB)
  char* ws = (char*)d_ws;
  u8*     WT8      = (u8*)ws;                          //  67,108,864 B
  u8*     h8       = (u8*)(ws + 67108864);             //   8,388,608 B
  float2* partials = (float2*)(ws + 75497472);         //  16,777,216 B
  float*  chlog    = (float*)(ws + 92274688);          //      16,384 B
  int*    chosen   = (int*)(ws + 92291072);            //      16,384 B
  float*  accum    = (float*)(ws + 92307456);          //          64 B (pad)
  int*    boff     = (int*)(ws + 92307520);            //       2,112 B (513+pad)
  int*    bent     = (int*)(ws + 92309632);            //      16,384 B

  (void)hipFuncSetAttribute((const void*)gemm_lse,
                            hipFuncAttributeMaxDynamicSharedMemorySize, 65536);

  init_k<<<16, 256, 0, stream>>>(ids, chosen, chlog, accum);
  bucket_k<<<1, 512, 0, stream>>>(chosen, boff, bent);
  conv_h<<<4096, 256, 0, stream>>>(hs, h8);
  transpose_w<<<dim3(512, 32), 256, 0, stream>>>(W, WT8, hs, boff, bent, chlog);
  gemm_lse<<<8192, 256, 65536, stream>>>(h8, WT8, partials);
  reduce_lse<<<1023, 256, 0, stream>>>(partials, chlog, oldlp, labels, adv, out, accum);
  finalize_k<<<1, 1, 0, stream>>>(accum, out);
}